// Round 4
// baseline (1060.711 us; speedup 1.0000x reference)
//
#include <hip/hip_runtime.h>
#include <hip/hip_bf16.h>

#define TSTEPS 1024
#define NIN 128
#define NL 64
#define NH 128
#define NOUT 32

typedef __attribute__((ext_vector_type(8))) short short8;
typedef __attribute__((ext_vector_type(4))) float f32x4;

__device__ inline int pk2(float x, float y) {
    __hip_bfloat162 h = __float22bfloat162_rn(make_float2(x, y));
    union { __hip_bfloat162 h; int i; } u;
    u.h = h;
    return u.i;
}
__device__ inline short8 pack8(float4 r0, float4 r1) {
    union { short8 s; int i[4]; } f;
    f.i[0] = pk2(r0.x, r0.y); f.i[1] = pk2(r0.z, r0.w);
    f.i[2] = pk2(r1.x, r1.y); f.i[3] = pk2(r1.z, r1.w);
    return f.s;
}

// ---------------------------------------------------------------------------
// Pass 1: u'[t][b][l] = bf16( C[l,:]·s[b,t,:] + h1[l] )   — verbatim round-0.
// ---------------------------------------------------------------------------
__launch_bounds__(256, 1)
__global__ void ugemm_mfma(const float* __restrict__ input,
                           const float* __restrict__ C,
                           const float* __restrict__ h1,
                           unsigned short* __restrict__ u16) {
    const int lane = threadIdx.x & 63;
    const int wv   = threadIdx.x >> 6;
    const int c = lane & 15;
    const int q = lane >> 4;
    const long wbase = ((long)blockIdx.x * 4 + wv) * 128;  // first row (b*1024+t)

    short8 cA[4][4];
    #pragma unroll
    for (int mt = 0; mt < 4; ++mt)
        #pragma unroll
        for (int kf = 0; kf < 4; ++kf) {
            const float* p = C + (mt * 16 + c) * NIN + kf * 32 + q * 8;
            cA[mt][kf] = pack8(*(const float4*)p, *(const float4*)(p + 4));
        }
    f32x4 h1f[4];
    #pragma unroll
    for (int mt = 0; mt < 4; ++mt)
        h1f[mt] = *(const f32x4*)(h1 + mt * 16 + q * 4);

    float4 raw[8], rawn[8];
    {
        const float* sr = input + (wbase + c) * NIN;
        #pragma unroll
        for (int kf = 0; kf < 4; ++kf) {
            raw[2*kf]   = *(const float4*)(sr + kf * 32 + q * 8);
            raw[2*kf+1] = *(const float4*)(sr + kf * 32 + q * 8 + 4);
        }
    }

    for (int it = 0; it < 8; ++it) {
        if (it < 7) {
            const float* sr = input + (wbase + (it + 1) * 16 + c) * NIN;
            #pragma unroll
            for (int kf = 0; kf < 4; ++kf) {
                rawn[2*kf]   = *(const float4*)(sr + kf * 32 + q * 8);
                rawn[2*kf+1] = *(const float4*)(sr + kf * 32 + q * 8 + 4);
            }
        }
        short8 bf[4];
        #pragma unroll
        for (int kf = 0; kf < 4; ++kf)
            bf[kf] = pack8(raw[2*kf], raw[2*kf+1]);
        long rr = wbase + it * 16 + c;
        int b = (int)(rr >> 10), t = (int)(rr & 1023);
        unsigned short* ubase = u16 + ((size_t)t * 256 + b) * 64 + q * 4;
        #pragma unroll
        for (int mt = 0; mt < 4; ++mt) {
            f32x4 acc = __builtin_amdgcn_mfma_f32_16x16x32_bf16(cA[mt][0], bf[0], h1f[mt], 0, 0, 0);
            acc = __builtin_amdgcn_mfma_f32_16x16x32_bf16(cA[mt][1], bf[1], acc, 0, 0, 0);
            acc = __builtin_amdgcn_mfma_f32_16x16x32_bf16(cA[mt][2], bf[2], acc, 0, 0, 0);
            acc = __builtin_amdgcn_mfma_f32_16x16x32_bf16(cA[mt][3], bf[3], acc, 0, 0, 0);
            *(int2*)(ubase + mt * 16) =
                make_int2(pk2(acc[0], acc[1]), pk2(acc[2], acc[3]));
        }
        #pragma unroll
        for (int j = 0; j < 8; ++j) raw[j] = rawn[j];
    }
}

// ---------------------------------------------------------------------------
// Pass 2: single-wave barrier-free scan. Grid 16 WGs x 64 thr; each wave owns
// one 16-batch group end to end. All weights replicated in registers; the two
// per-step transposes (z -> B-frag, H -> B-frag) are wave-private LDS round
// trips with no s_barrier. Reads are structured so bh[kt] depends only on
// H-tiles 2kt,2kt+1 (fine-grained lgkmcnt pipelining).
// ---------------------------------------------------------------------------
__launch_bounds__(64, 1)
__global__ void plrnn_scan1w(const float* __restrict__ A,
                             const float* __restrict__ W1,
                             const float* __restrict__ W2,
                             const float* __restrict__ h2,
                             const unsigned short* __restrict__ u16,
                             const float* __restrict__ Wout,
                             const float* __restrict__ bout,
                             float* __restrict__ out) {
    __shared__ __attribute__((aligned(16))) unsigned short zbuf[16 * 72];
    __shared__ __attribute__((aligned(16))) unsigned short hbuf[16 * 136];

    const int lane = threadIdx.x & 63;
    const int c = lane & 15;               // batch col
    const int q = lane >> 4;               // quad
    const int bbase = blockIdx.x * 16;

    // ---- full weight set in registers (per wave) ----
    short8 aw2[8][2];   // 8 H-tiles, K=64 (2 frags)
    #pragma unroll
    for (int i = 0; i < 8; ++i)
        #pragma unroll
        for (int kt = 0; kt < 2; ++kt) {
            const float* p = W2 + (i * 16 + c) * NL + kt * 32 + q * 8;
            aw2[i][kt] = pack8(*(const float4*)p, *(const float4*)(p + 4));
        }
    short8 aw1[4][4];   // 4 Z-tiles, K=128 (4 frags)
    #pragma unroll
    for (int lt = 0; lt < 4; ++lt)
        #pragma unroll
        for (int kt = 0; kt < 4; ++kt) {
            const float* p = W1 + (lt * 16 + c) * NH + kt * 32 + q * 8;
            aw1[lt][kt] = pack8(*(const float4*)p, *(const float4*)(p + 4));
        }
    f32x4 h2f[8];
    #pragma unroll
    for (int i = 0; i < 8; ++i) h2f[i] = *(const f32x4*)(h2 + i * 16 + q * 4);
    f32x4 af[4];
    #pragma unroll
    for (int lt = 0; lt < 4; ++lt) af[lt] = *(const f32x4*)(A + lt * 16 + q * 4);

    f32x4 zf[4] = {{0.f,0.f,0.f,0.f},{0.f,0.f,0.f,0.f},
                   {0.f,0.f,0.f,0.f},{0.f,0.f,0.f,0.f}};

    // u' stream: lane (q,c) needs int2 at (bbase+c)*64 + lt*16 + q*4, per t
    const unsigned short* ub = u16 + ((size_t)(bbase + c)) * 64 + q * 4;
    int2 ucur[4], unx[4];
    #pragma unroll
    for (int lt = 0; lt < 4; ++lt) ucur[lt] = *(const int2*)(ub + lt * 16);
    #pragma unroll
    for (int lt = 0; lt < 4; ++lt) unx[lt]  = *(const int2*)(ub + 16384 + lt * 16);

    for (int t = 0; t < TSTEPS; ++t) {
        // prefetch u'(t+2) — in flight across the whole step
        int2 upf[4];
        {
            const int tp = (t + 2 < TSTEPS) ? t + 2 : TSTEPS - 1;
            const unsigned short* up = ub + (size_t)tp * 16384;
            #pragma unroll
            for (int lt = 0; lt < 4; ++lt) upf[lt] = *(const int2*)(up + lt * 16);
        }

        // ---- pack z -> LDS (4x b64, wave-private) ----
        #pragma unroll
        for (int lt = 0; lt < 4; ++lt)
            *(int2*)&zbuf[c * 72 + lt * 16 + q * 4] =
                make_int2(pk2(zf[lt][0], zf[lt][1]), pk2(zf[lt][2], zf[lt][3]));

        // cin = A*z + u'  (VALU; fills the LDS write->read latency)
        f32x4 cin[4];
        #pragma unroll
        for (int lt = 0; lt < 4; ++lt) {
            cin[lt][0] = fmaf(zf[lt][0], af[lt][0], __int_as_float(ucur[lt].x << 16));
            cin[lt][1] = fmaf(zf[lt][1], af[lt][1], __int_as_float(ucur[lt].x & 0xffff0000));
            cin[lt][2] = fmaf(zf[lt][2], af[lt][2], __int_as_float(ucur[lt].y << 16));
            cin[lt][3] = fmaf(zf[lt][3], af[lt][3], __int_as_float(ucur[lt].y & 0xffff0000));
        }

        // ---- z B-frags ----
        short8 bz0 = *(const short8*)&zbuf[c * 72 + q * 8];
        short8 bz1 = *(const short8*)&zbuf[c * 72 + 32 + q * 8];

        // ---- MFMA1: 8 H-tiles = relu(W2 @ z + h2) -> LDS ----
        #pragma unroll
        for (int i = 0; i < 8; ++i) {
            f32x4 acc = __builtin_amdgcn_mfma_f32_16x16x32_bf16(aw2[i][0], bz0, h2f[i], 0, 0, 0);
            acc = __builtin_amdgcn_mfma_f32_16x16x32_bf16(aw2[i][1], bz1, acc, 0, 0, 0);
            *(int2*)&hbuf[c * 136 + i * 16 + q * 4] =
                make_int2(pk2(fmaxf(acc[0], 0.f), fmaxf(acc[1], 0.f)),
                          pk2(fmaxf(acc[2], 0.f), fmaxf(acc[3], 0.f)));
        }

        // ---- MFMA2: z' = clip(cin + W1 @ H); bh[kt] needs only tiles 2kt,2kt+1 ----
        #pragma unroll
        for (int kt = 0; kt < 4; ++kt) {
            short8 bh = *(const short8*)&hbuf[c * 136 + kt * 32 + q * 8];
            #pragma unroll
            for (int lt = 0; lt < 4; ++lt)
                cin[lt] = __builtin_amdgcn_mfma_f32_16x16x32_bf16(aw1[lt][kt], bh, cin[lt], 0, 0, 0);
        }
        #pragma unroll
        for (int lt = 0; lt < 4; ++lt)
            #pragma unroll
            for (int e = 0; e < 4; ++e)
                zf[lt][e] = fminf(fmaxf(cin[lt][e], -5.f), 5.f);

        // rotate u pipeline
        #pragma unroll
        for (int lt = 0; lt < 4; ++lt) { ucur[lt] = unx[lt]; unx[lt] = upf[lt]; }
    }

    // ---- epilogue: out = Wout @ z + bout (both m-tiles in this wave) ----
    #pragma unroll
    for (int lt = 0; lt < 4; ++lt)
        *(int2*)&zbuf[c * 72 + lt * 16 + q * 4] =
            make_int2(pk2(zf[lt][0], zf[lt][1]), pk2(zf[lt][2], zf[lt][3]));
    short8 fz0 = *(const short8*)&zbuf[c * 72 + q * 8];
    short8 fz1 = *(const short8*)&zbuf[c * 72 + 32 + q * 8];
    #pragma unroll
    for (int mt = 0; mt < 2; ++mt) {
        const float* p0 = Wout + (mt * 16 + c) * NL + q * 8;
        short8 fa = pack8(*(const float4*)p0, *(const float4*)(p0 + 4));
        short8 fb = pack8(*(const float4*)(p0 + 32), *(const float4*)(p0 + 36));
        f32x4 cb = *(const f32x4*)(bout + mt * 16 + q * 4);
        f32x4 acc = __builtin_amdgcn_mfma_f32_16x16x32_bf16(fa, fz0, cb, 0, 0, 0);
        acc = __builtin_amdgcn_mfma_f32_16x16x32_bf16(fb, fz1, acc, 0, 0, 0);
        *(f32x4*)&out[(bbase + c) * NOUT + mt * 16 + q * 4] = acc;
    }
}

extern "C" void kernel_launch(void* const* d_in, const int* in_sizes, int n_in,
                              void* d_out, int out_size, void* d_ws, size_t ws_size,
                              hipStream_t stream) {
    const float* input = (const float*)d_in[0];
    const float* A     = (const float*)d_in[1];
    const float* W1    = (const float*)d_in[2];
    const float* W2    = (const float*)d_in[3];
    const float* h1    = (const float*)d_in[4];
    const float* h2    = (const float*)d_in[5];
    const float* C     = (const float*)d_in[6];
    const float* Wout  = (const float*)d_in[7];
    const float* bout  = (const float*)d_in[8];
    float* out = (float*)d_out;

    unsigned short* u16 = (unsigned short*)d_ws;   // 256*1024*64 bf16 = 33.5 MB

    ugemm_mfma<<<dim3(512), dim3(256), 0, stream>>>(input, C, h1, u16);
    plrnn_scan1w<<<dim3(16), dim3(64), 0, stream>>>(
        A, W1, W2, h2, u16, Wout, bout, out);
}

// Round 5
// 1031.228 us; speedup vs baseline: 1.0286x; 1.0286x over previous
//
#include <hip/hip_runtime.h>
#include <hip/hip_bf16.h>

#define TSTEPS 1024
#define NIN 128
#define NL 64
#define NH 128
#define NOUT 32

typedef __attribute__((ext_vector_type(8))) short short8;
typedef __attribute__((ext_vector_type(4))) float f32x4;

__device__ inline int pk2(float x, float y) {
    __hip_bfloat162 h = __float22bfloat162_rn(make_float2(x, y));
    union { __hip_bfloat162 h; int i; } u;
    u.h = h;
    return u.i;
}
__device__ inline short8 pack8(float4 r0, float4 r1) {
    union { short8 s; int i[4]; } f;
    f.i[0] = pk2(r0.x, r0.y); f.i[1] = pk2(r0.z, r0.w);
    f.i[2] = pk2(r1.x, r1.y); f.i[3] = pk2(r1.z, r1.w);
    return f.s;
}
__device__ inline short8 mk8(int a, int b, int cc, int d) {
    union { short8 s; int i[4]; } f;
    f.i[0] = a; f.i[1] = b; f.i[2] = cc; f.i[3] = d;
    return f.s;
}

// Latent permutation: row (lt*16 + mloc) of the tilde-matrix = natural row
//   l(lt, mloc) = 32*(lt>>1) + 8*(mloc>>2) + 4*(lt&1) + (mloc&3)        (64-wide)
// Hidden permutation (128-wide, 8 tiles):
//   lH(i, mloc) = 64*(i>>2) + 32*((i>>1)&1) + 8*(mloc>>2) + 4*(i&1) + (mloc&3)
// With these, MFMA D output (lane q rows 4q+e) packs DIRECTLY into the next
// MFMA's B-fragment (lane q ks 8q+j) — no transpose, no LDS, no cross-lane.

// ---------------------------------------------------------------------------
// Pass 1: u'[t][b][s] = bf16( C[l(mt,mloc),:]·s[b,t,:] + h1[l(mt,mloc)] )
// Identical mechanics to the verified round-0 kernel; only C/h1 rows are
// loaded through the static permutation so u16 storage is in tilde order.
// ---------------------------------------------------------------------------
__launch_bounds__(256, 1)
__global__ void ugemm_mfma(const float* __restrict__ input,
                           const float* __restrict__ C,
                           const float* __restrict__ h1,
                           unsigned short* __restrict__ u16) {
    const int lane = threadIdx.x & 63;
    const int wv   = threadIdx.x >> 6;
    const int c = lane & 15;
    const int q = lane >> 4;
    const long wbase = ((long)blockIdx.x * 4 + wv) * 128;  // first row (b*1024+t)

    short8 cA[4][4];
    #pragma unroll
    for (int mt = 0; mt < 4; ++mt) {
        const int row = 32 * (mt >> 1) + 8 * (c >> 2) + 4 * (mt & 1) + (c & 3);
        #pragma unroll
        for (int kf = 0; kf < 4; ++kf) {
            const float* p = C + row * NIN + kf * 32 + q * 8;
            cA[mt][kf] = pack8(*(const float4*)p, *(const float4*)(p + 4));
        }
    }
    f32x4 h1f[4];
    #pragma unroll
    for (int mt = 0; mt < 4; ++mt)
        h1f[mt] = *(const f32x4*)(h1 + 32 * (mt >> 1) + 4 * (mt & 1) + 8 * q);

    float4 raw[8], rawn[8];
    {
        const float* sr = input + (wbase + c) * NIN;
        #pragma unroll
        for (int kf = 0; kf < 4; ++kf) {
            raw[2*kf]   = *(const float4*)(sr + kf * 32 + q * 8);
            raw[2*kf+1] = *(const float4*)(sr + kf * 32 + q * 8 + 4);
        }
    }

    for (int it = 0; it < 8; ++it) {
        if (it < 7) {
            const float* sr = input + (wbase + (it + 1) * 16 + c) * NIN;
            #pragma unroll
            for (int kf = 0; kf < 4; ++kf) {
                rawn[2*kf]   = *(const float4*)(sr + kf * 32 + q * 8);
                rawn[2*kf+1] = *(const float4*)(sr + kf * 32 + q * 8 + 4);
            }
        }
        short8 bf[4];
        #pragma unroll
        for (int kf = 0; kf < 4; ++kf)
            bf[kf] = pack8(raw[2*kf], raw[2*kf+1]);
        long rr = wbase + it * 16 + c;
        int b = (int)(rr >> 10), t = (int)(rr & 1023);
        unsigned short* ubase = u16 + ((size_t)t * 256 + b) * 64 + q * 4;
        #pragma unroll
        for (int mt = 0; mt < 4; ++mt) {
            f32x4 acc = __builtin_amdgcn_mfma_f32_16x16x32_bf16(cA[mt][0], bf[0], h1f[mt], 0, 0, 0);
            acc = __builtin_amdgcn_mfma_f32_16x16x32_bf16(cA[mt][1], bf[1], acc, 0, 0, 0);
            acc = __builtin_amdgcn_mfma_f32_16x16x32_bf16(cA[mt][2], bf[2], acc, 0, 0, 0);
            acc = __builtin_amdgcn_mfma_f32_16x16x32_bf16(cA[mt][3], bf[3], acc, 0, 0, 0);
            *(int2*)(ubase + mt * 16) =
                make_int2(pk2(acc[0], acc[1]), pk2(acc[2], acc[3]));
        }
        #pragma unroll
        for (int j = 0; j < 8; ++j) raw[j] = rawn[j];
    }
}

// ---------------------------------------------------------------------------
// Pass 2: register-only scan. Grid 16 WGs x 64 thr; one wave owns one
// 16-batch group end to end. Weights pre-permuted so each MFMA's output
// registers repack (pk2 only) into the next MFMA's B-fragments. No LDS,
// no barriers, no cross-lane ops in the loop.
// ---------------------------------------------------------------------------
__launch_bounds__(64, 1)
__global__ void plrnn_scan_reg(const float* __restrict__ A,
                               const float* __restrict__ W1,
                               const float* __restrict__ W2,
                               const float* __restrict__ h2,
                               const unsigned short* __restrict__ u16,
                               const float* __restrict__ Wout,
                               const float* __restrict__ bout,
                               float* __restrict__ out) {
    const int lane = threadIdx.x & 63;
    const int c = lane & 15;               // batch col
    const int q = lane >> 4;               // quad
    const int bbase = blockIdx.x * 16;

    // ---- W2-tilde: rows lH-permuted, columns natural ----
    short8 aw2[8][2];
    #pragma unroll
    for (int i = 0; i < 8; ++i) {
        const int row = 64 * (i >> 2) + 32 * ((i >> 1) & 1) + 8 * (c >> 2)
                      + 4 * (i & 1) + (c & 3);
        #pragma unroll
        for (int kt = 0; kt < 2; ++kt) {
            const float* p = W2 + row * NL + kt * 32 + q * 8;
            aw2[i][kt] = pack8(*(const float4*)p, *(const float4*)(p + 4));
        }
    }
    // ---- W1-tilde: rows l-permuted, columns natural ----
    short8 aw1[4][4];
    #pragma unroll
    for (int lt = 0; lt < 4; ++lt) {
        const int row = 32 * (lt >> 1) + 8 * (c >> 2) + 4 * (lt & 1) + (c & 3);
        #pragma unroll
        for (int kt = 0; kt < 4; ++kt) {
            const float* p = W1 + row * NH + kt * 32 + q * 8;
            aw1[lt][kt] = pack8(*(const float4*)p, *(const float4*)(p + 4));
        }
    }
    // ---- permuted biases / diagonal ----
    f32x4 h2f[8];
    #pragma unroll
    for (int i = 0; i < 8; ++i)
        h2f[i] = *(const f32x4*)(h2 + 64 * (i >> 2) + 32 * ((i >> 1) & 1)
                                 + 4 * (i & 1) + 8 * q);
    f32x4 af[4];
    #pragma unroll
    for (int lt = 0; lt < 4; ++lt)
        af[lt] = *(const f32x4*)(A + 32 * (lt >> 1) + 4 * (lt & 1) + 8 * q);

    f32x4 zf[4] = {{0.f,0.f,0.f,0.f},{0.f,0.f,0.f,0.f},
                   {0.f,0.f,0.f,0.f},{0.f,0.f,0.f,0.f}};

    // u' stream in tilde order; per-t stride 16384 shorts. 3-deep pipeline.
    const unsigned short* ub = u16 + ((size_t)(bbase + c)) * 64 + q * 4;
    int2 u0[4], u1[4], u2[4];
    #pragma unroll
    for (int lt = 0; lt < 4; ++lt) u0[lt] = *(const int2*)(ub + lt * 16);
    #pragma unroll
    for (int lt = 0; lt < 4; ++lt) u1[lt] = *(const int2*)(ub + 16384 + lt * 16);
    #pragma unroll
    for (int lt = 0; lt < 4; ++lt) u2[lt] = *(const int2*)(ub + 32768 + lt * 16);

    for (int t = 0; t < TSTEPS; ++t) {
        // prefetch u'(t+3)
        int2 upf[4];
        {
            const int tp = (t + 3 < TSTEPS) ? t + 3 : TSTEPS - 1;
            const unsigned short* up = ub + (size_t)tp * 16384;
            #pragma unroll
            for (int lt = 0; lt < 4; ++lt) upf[lt] = *(const int2*)(up + lt * 16);
        }

        // ---- bz frags directly from zf (pure pk2, no movement) ----
        short8 bz0 = mk8(pk2(zf[0][0], zf[0][1]), pk2(zf[0][2], zf[0][3]),
                         pk2(zf[1][0], zf[1][1]), pk2(zf[1][2], zf[1][3]));
        short8 bz1 = mk8(pk2(zf[2][0], zf[2][1]), pk2(zf[2][2], zf[2][3]),
                         pk2(zf[3][0], zf[3][1]), pk2(zf[3][2], zf[3][3]));

        // ---- cin = A*z + u' (f32, off the MFMA1 path) ----
        f32x4 cin[4];
        #pragma unroll
        for (int lt = 0; lt < 4; ++lt) {
            cin[lt][0] = fmaf(zf[lt][0], af[lt][0], __int_as_float(u0[lt].x << 16));
            cin[lt][1] = fmaf(zf[lt][1], af[lt][1], __int_as_float(u0[lt].x & 0xffff0000));
            cin[lt][2] = fmaf(zf[lt][2], af[lt][2], __int_as_float(u0[lt].y << 16));
            cin[lt][3] = fmaf(zf[lt][3], af[lt][3], __int_as_float(u0[lt].y & 0xffff0000));
        }

        // ---- MFMA1: 8 H-tiles = relu(W2~ @ z + h2~), stays in registers ----
        f32x4 ha[8];
        #pragma unroll
        for (int i = 0; i < 8; ++i) {
            ha[i] = __builtin_amdgcn_mfma_f32_16x16x32_bf16(aw2[i][0], bz0, h2f[i], 0, 0, 0);
            ha[i] = __builtin_amdgcn_mfma_f32_16x16x32_bf16(aw2[i][1], bz1, ha[i], 0, 0, 0);
        }

        // ---- bh frags: relu + pk2 of own registers ----
        short8 bh[4];
        #pragma unroll
        for (int kt = 0; kt < 4; ++kt) {
            const int i0 = 2 * kt, i1 = 2 * kt + 1;
            bh[kt] = mk8(
                pk2(fmaxf(ha[i0][0], 0.f), fmaxf(ha[i0][1], 0.f)),
                pk2(fmaxf(ha[i0][2], 0.f), fmaxf(ha[i0][3], 0.f)),
                pk2(fmaxf(ha[i1][0], 0.f), fmaxf(ha[i1][1], 0.f)),
                pk2(fmaxf(ha[i1][2], 0.f), fmaxf(ha[i1][3], 0.f)));
        }

        // ---- MFMA2: z' = clip(cin + W1~ @ H) ----
        #pragma unroll
        for (int kt = 0; kt < 4; ++kt)
            #pragma unroll
            for (int lt = 0; lt < 4; ++lt)
                cin[lt] = __builtin_amdgcn_mfma_f32_16x16x32_bf16(aw1[lt][kt], bh[kt], cin[lt], 0, 0, 0);
        #pragma unroll
        for (int lt = 0; lt < 4; ++lt)
            #pragma unroll
            for (int e = 0; e < 4; ++e)
                zf[lt][e] = fminf(fmaxf(cin[lt][e], -5.f), 5.f);

        // rotate u pipeline
        #pragma unroll
        for (int lt = 0; lt < 4; ++lt) { u0[lt] = u1[lt]; u1[lt] = u2[lt]; u2[lt] = upf[lt]; }
    }

    // ---- epilogue: out = Wout @ z + bout (k-slots are natural latents) ----
    short8 fz0 = mk8(pk2(zf[0][0], zf[0][1]), pk2(zf[0][2], zf[0][3]),
                     pk2(zf[1][0], zf[1][1]), pk2(zf[1][2], zf[1][3]));
    short8 fz1 = mk8(pk2(zf[2][0], zf[2][1]), pk2(zf[2][2], zf[2][3]),
                     pk2(zf[3][0], zf[3][1]), pk2(zf[3][2], zf[3][3]));
    #pragma unroll
    for (int mt = 0; mt < 2; ++mt) {
        const float* p0 = Wout + (mt * 16 + c) * NL + q * 8;
        short8 fa = pack8(*(const float4*)p0, *(const float4*)(p0 + 4));
        short8 fb = pack8(*(const float4*)(p0 + 32), *(const float4*)(p0 + 36));
        f32x4 cb = *(const f32x4*)(bout + mt * 16 + q * 4);
        f32x4 acc = __builtin_amdgcn_mfma_f32_16x16x32_bf16(fa, fz0, cb, 0, 0, 0);
        acc = __builtin_amdgcn_mfma_f32_16x16x32_bf16(fb, fz1, acc, 0, 0, 0);
        *(f32x4*)&out[(bbase + c) * NOUT + mt * 16 + q * 4] = acc;
    }
}

extern "C" void kernel_launch(void* const* d_in, const int* in_sizes, int n_in,
                              void* d_out, int out_size, void* d_ws, size_t ws_size,
                              hipStream_t stream) {
    const float* input = (const float*)d_in[0];
    const float* A     = (const float*)d_in[1];
    const float* W1    = (const float*)d_in[2];
    const float* W2    = (const float*)d_in[3];
    const float* h1    = (const float*)d_in[4];
    const float* h2    = (const float*)d_in[5];
    const float* C     = (const float*)d_in[6];
    const float* Wout  = (const float*)d_in[7];
    const float* bout  = (const float*)d_in[8];
    float* out = (float*)d_out;

    unsigned short* u16 = (unsigned short*)d_ws;   // 256*1024*64 bf16 = 33.5 MB

    ugemm_mfma<<<dim3(512), dim3(256), 0, stream>>>(input, C, h1, u16);
    plrnn_scan_reg<<<dim3(16), dim3(64), 0, stream>>>(
        A, W1, W2, h2, u16, Wout, bout, out);
}

// Round 6
// 910.019 us; speedup vs baseline: 1.1656x; 1.1332x over previous
//
#include <hip/hip_runtime.h>
#include <hip/hip_bf16.h>

#define TSTEPS 1024
#define NIN 128
#define NL 64
#define NH 128
#define NOUT 32

typedef __attribute__((ext_vector_type(8))) short short8;
typedef __attribute__((ext_vector_type(4))) float f32x4;

__device__ inline int pk2(float x, float y) {
    __hip_bfloat162 h = __float22bfloat162_rn(make_float2(x, y));
    union { __hip_bfloat162 h; int i; } u;
    u.h = h;
    return u.i;
}
__device__ inline short8 pack8(float4 r0, float4 r1) {
    union { short8 s; int i[4]; } f;
    f.i[0] = pk2(r0.x, r0.y); f.i[1] = pk2(r0.z, r0.w);
    f.i[2] = pk2(r1.x, r1.y); f.i[3] = pk2(r1.z, r1.w);
    return f.s;
}
__device__ inline short8 mk8(int a, int b, int cc, int d) {
    union { short8 s; int i[4]; } f;
    f.i[0] = a; f.i[1] = b; f.i[2] = cc; f.i[3] = d;
    return f.s;
}
__device__ inline void gload16(const unsigned short* g, unsigned short* l) {
    __builtin_amdgcn_global_load_lds(
        (const __attribute__((address_space(1))) unsigned int*)g,
        (__attribute__((address_space(3))) unsigned int*)l, 16, 0, 0);
}

// Latent permutation (as round 5, verified passing):
//   l(lt, mloc) = 32*(lt>>1) + 8*(mloc>>2) + 4*(lt&1) + (mloc&3)
//   lH(i, mloc) = 64*(i>>2) + 32*((i>>1)&1) + 8*(mloc>>2) + 4*(i&1) + (mloc&3)
// u16 storage (NEW): per (t, group g) a 2 KB lane-linear block:
//   shorts offset = ((t*16+g)*1024) + half*512 + q*128 + cb*8 + (mt&1)*4 + e
//   (half = mt>>1) so that consumer lane l=(q*16+c) reads 16 B at l*16 (+1 KB).

// ---------------------------------------------------------------------------
// Pass 1: u' = bf16(C~ @ s + h1~), stored in lane-linear block order.
// ---------------------------------------------------------------------------
__launch_bounds__(256, 1)
__global__ void ugemm_mfma(const float* __restrict__ input,
                           const float* __restrict__ C,
                           const float* __restrict__ h1,
                           unsigned short* __restrict__ u16) {
    const int lane = threadIdx.x & 63;
    const int wv   = threadIdx.x >> 6;
    const int c = lane & 15;
    const int q = lane >> 4;
    const long wbase = ((long)blockIdx.x * 4 + wv) * 128;  // first row (b*1024+t)

    short8 cA[4][4];
    #pragma unroll
    for (int mt = 0; mt < 4; ++mt) {
        const int row = 32 * (mt >> 1) + 8 * (c >> 2) + 4 * (mt & 1) + (c & 3);
        #pragma unroll
        for (int kf = 0; kf < 4; ++kf) {
            const float* p = C + row * NIN + kf * 32 + q * 8;
            cA[mt][kf] = pack8(*(const float4*)p, *(const float4*)(p + 4));
        }
    }
    f32x4 h1f[4];
    #pragma unroll
    for (int mt = 0; mt < 4; ++mt)
        h1f[mt] = *(const f32x4*)(h1 + 32 * (mt >> 1) + 4 * (mt & 1) + 8 * q);

    float4 raw[8], rawn[8];
    {
        const float* sr = input + (wbase + c) * NIN;
        #pragma unroll
        for (int kf = 0; kf < 4; ++kf) {
            raw[2*kf]   = *(const float4*)(sr + kf * 32 + q * 8);
            raw[2*kf+1] = *(const float4*)(sr + kf * 32 + q * 8 + 4);
        }
    }

    for (int it = 0; it < 8; ++it) {
        if (it < 7) {
            const float* sr = input + (wbase + (it + 1) * 16 + c) * NIN;
            #pragma unroll
            for (int kf = 0; kf < 4; ++kf) {
                rawn[2*kf]   = *(const float4*)(sr + kf * 32 + q * 8);
                rawn[2*kf+1] = *(const float4*)(sr + kf * 32 + q * 8 + 4);
            }
        }
        short8 bf[4];
        #pragma unroll
        for (int kf = 0; kf < 4; ++kf)
            bf[kf] = pack8(raw[2*kf], raw[2*kf+1]);
        long rr = wbase + it * 16 + c;
        int b = (int)(rr >> 10), t = (int)(rr & 1023);
        const int g = b >> 4, cb = b & 15;
        unsigned short* ubase = u16 + ((size_t)t * 16 + g) * 1024 + q * 128 + cb * 8;
        #pragma unroll
        for (int mt = 0; mt < 4; ++mt) {
            f32x4 acc = __builtin_amdgcn_mfma_f32_16x16x32_bf16(cA[mt][0], bf[0], h1f[mt], 0, 0, 0);
            acc = __builtin_amdgcn_mfma_f32_16x16x32_bf16(cA[mt][1], bf[1], acc, 0, 0, 0);
            acc = __builtin_amdgcn_mfma_f32_16x16x32_bf16(cA[mt][2], bf[2], acc, 0, 0, 0);
            acc = __builtin_amdgcn_mfma_f32_16x16x32_bf16(cA[mt][3], bf[3], acc, 0, 0, 0);
            *(int2*)(ubase + (mt >> 1) * 512 + (mt & 1) * 4) =
                make_int2(pk2(acc[0], acc[1]), pk2(acc[2], acc[3]));
        }
        #pragma unroll
        for (int j = 0; j < 8; ++j) raw[j] = rawn[j];
    }
}

// ---------------------------------------------------------------------------
// Pass 2: register-only scan + compiler-proof u' pipeline.
// Grid 16 WGs x 64 thr; one wave owns one 16-batch group. u' streamed via
// global_load_lds ring (8 slots x 2KB, issued 4 steps ahead, hand-counted
// vmcnt) -> ds_read_b128 one step ahead -> registers. No barriers.
// ---------------------------------------------------------------------------
__launch_bounds__(64, 1)
__global__ void plrnn_scan_reg(const float* __restrict__ A,
                               const float* __restrict__ W1,
                               const float* __restrict__ W2,
                               const float* __restrict__ h2,
                               const unsigned short* __restrict__ u16,
                               const float* __restrict__ Wout,
                               const float* __restrict__ bout,
                               float* __restrict__ out) {
    __shared__ __attribute__((aligned(16))) unsigned short ulds[8 * 1024];  // 16 KB ring

    const int lane = threadIdx.x & 63;
    const int c = lane & 15;               // batch col
    const int q = lane >> 4;               // quad
    const int g = blockIdx.x;
    const int bbase = g * 16;

    // ---- W2-tilde ----
    short8 aw2[8][2];
    #pragma unroll
    for (int i = 0; i < 8; ++i) {
        const int row = 64 * (i >> 2) + 32 * ((i >> 1) & 1) + 8 * (c >> 2)
                      + 4 * (i & 1) + (c & 3);
        #pragma unroll
        for (int kt = 0; kt < 2; ++kt) {
            const float* p = W2 + row * NL + kt * 32 + q * 8;
            aw2[i][kt] = pack8(*(const float4*)p, *(const float4*)(p + 4));
        }
    }
    // ---- W1-tilde ----
    short8 aw1[4][4];
    #pragma unroll
    for (int lt = 0; lt < 4; ++lt) {
        const int row = 32 * (lt >> 1) + 8 * (c >> 2) + 4 * (lt & 1) + (c & 3);
        #pragma unroll
        for (int kt = 0; kt < 4; ++kt) {
            const float* p = W1 + row * NH + kt * 32 + q * 8;
            aw1[lt][kt] = pack8(*(const float4*)p, *(const float4*)(p + 4));
        }
    }
    f32x4 h2f[8];
    #pragma unroll
    for (int i = 0; i < 8; ++i)
        h2f[i] = *(const f32x4*)(h2 + 64 * (i >> 2) + 32 * ((i >> 1) & 1)
                                 + 4 * (i & 1) + 8 * q);
    f32x4 af[4];
    #pragma unroll
    for (int lt = 0; lt < 4; ++lt)
        af[lt] = *(const f32x4*)(A + 32 * (lt >> 1) + 4 * (lt & 1) + 8 * q);

    f32x4 zf[4] = {{0.f,0.f,0.f,0.f},{0.f,0.f,0.f,0.f},
                   {0.f,0.f,0.f,0.f},{0.f,0.f,0.f,0.f}};

    // per-lane global source base (16B per lane, second KB at +512 shorts)
    const unsigned short* gs0 = u16 + (size_t)g * 1024 + lane * 8;

    // ---- prologue: stage steps 0..3 into ring slots 0..3 ----
    #pragma unroll
    for (int s0 = 0; s0 < 4; ++s0) {
        const unsigned short* p0 = gs0 + (size_t)s0 * 16384;
        unsigned short* l0 = &ulds[s0 * 1024];
        gload16(p0, l0);
        gload16(p0 + 512, l0 + 512);
    }
    __builtin_amdgcn_sched_barrier(0);
    asm volatile("s_waitcnt vmcnt(6)" ::: "memory");   // step 0 landed
    __builtin_amdgcn_sched_barrier(0);
    int4 uc0 = *(const int4*)(&ulds[0]   + lane * 8);
    int4 uc1 = *(const int4*)(&ulds[512] + lane * 8);

    for (int s = 0; s < TSTEPS; ++s) {
        // 1. issue staging for step s+4 (fire-and-forget, rides across steps)
        {
            const int tt = (s + 4 < TSTEPS) ? s + 4 : TSTEPS - 1;
            const unsigned short* p0 = gs0 + (size_t)tt * 16384;
            unsigned short* l0 = &ulds[((s + 4) & 7) * 1024];
            gload16(p0, l0);
            gload16(p0 + 512, l0 + 512);
        }
        __builtin_amdgcn_sched_barrier(0);
        asm volatile("s_waitcnt vmcnt(4)" ::: "memory");   // step s+1 landed
        __builtin_amdgcn_sched_barrier(0);
        // 2. LDS -> reg prefetch of step s+1 (consumed next iteration)
        const unsigned short* slot = &ulds[((s + 1) & 7) * 1024];
        int4 un0 = *(const int4*)(slot + lane * 8);
        int4 un1 = *(const int4*)(slot + 512 + lane * 8);

        // 3. compute step s (bit-identical to round-5 math)
        short8 bz0 = mk8(pk2(zf[0][0], zf[0][1]), pk2(zf[0][2], zf[0][3]),
                         pk2(zf[1][0], zf[1][1]), pk2(zf[1][2], zf[1][3]));
        short8 bz1 = mk8(pk2(zf[2][0], zf[2][1]), pk2(zf[2][2], zf[2][3]),
                         pk2(zf[3][0], zf[3][1]), pk2(zf[3][2], zf[3][3]));

        f32x4 cin[4];
        {
            const int ia0 = uc0.x, ib0 = uc0.y, ia1 = uc0.z, ib1 = uc0.w;
            const int ia2 = uc1.x, ib2 = uc1.y, ia3 = uc1.z, ib3 = uc1.w;
            cin[0][0] = fmaf(zf[0][0], af[0][0], __int_as_float(ia0 << 16));
            cin[0][1] = fmaf(zf[0][1], af[0][1], __int_as_float(ia0 & 0xffff0000));
            cin[0][2] = fmaf(zf[0][2], af[0][2], __int_as_float(ib0 << 16));
            cin[0][3] = fmaf(zf[0][3], af[0][3], __int_as_float(ib0 & 0xffff0000));
            cin[1][0] = fmaf(zf[1][0], af[1][0], __int_as_float(ia1 << 16));
            cin[1][1] = fmaf(zf[1][1], af[1][1], __int_as_float(ia1 & 0xffff0000));
            cin[1][2] = fmaf(zf[1][2], af[1][2], __int_as_float(ib1 << 16));
            cin[1][3] = fmaf(zf[1][3], af[1][3], __int_as_float(ib1 & 0xffff0000));
            cin[2][0] = fmaf(zf[2][0], af[2][0], __int_as_float(ia2 << 16));
            cin[2][1] = fmaf(zf[2][1], af[2][1], __int_as_float(ia2 & 0xffff0000));
            cin[2][2] = fmaf(zf[2][2], af[2][2], __int_as_float(ib2 << 16));
            cin[2][3] = fmaf(zf[2][3], af[2][3], __int_as_float(ib2 & 0xffff0000));
            cin[3][0] = fmaf(zf[3][0], af[3][0], __int_as_float(ia3 << 16));
            cin[3][1] = fmaf(zf[3][1], af[3][1], __int_as_float(ia3 & 0xffff0000));
            cin[3][2] = fmaf(zf[3][2], af[3][2], __int_as_float(ib3 << 16));
            cin[3][3] = fmaf(zf[3][3], af[3][3], __int_as_float(ib3 & 0xffff0000));
        }

        // MFMA1: 8 H-tiles = relu(W2~ @ z + h2~), in registers
        f32x4 ha[8];
        #pragma unroll
        for (int i = 0; i < 8; ++i) {
            ha[i] = __builtin_amdgcn_mfma_f32_16x16x32_bf16(aw2[i][0], bz0, h2f[i], 0, 0, 0);
            ha[i] = __builtin_amdgcn_mfma_f32_16x16x32_bf16(aw2[i][1], bz1, ha[i], 0, 0, 0);
        }
        short8 bh[4];
        #pragma unroll
        for (int kt = 0; kt < 4; ++kt) {
            const int i0 = 2 * kt, i1 = 2 * kt + 1;
            bh[kt] = mk8(
                pk2(fmaxf(ha[i0][0], 0.f), fmaxf(ha[i0][1], 0.f)),
                pk2(fmaxf(ha[i0][2], 0.f), fmaxf(ha[i0][3], 0.f)),
                pk2(fmaxf(ha[i1][0], 0.f), fmaxf(ha[i1][1], 0.f)),
                pk2(fmaxf(ha[i1][2], 0.f), fmaxf(ha[i1][3], 0.f)));
        }
        // MFMA2: z' = clip(cin + W1~ @ H)
        #pragma unroll
        for (int kt = 0; kt < 4; ++kt)
            #pragma unroll
            for (int lt = 0; lt < 4; ++lt)
                cin[lt] = __builtin_amdgcn_mfma_f32_16x16x32_bf16(aw1[lt][kt], bh[kt], cin[lt], 0, 0, 0);
        #pragma unroll
        for (int lt = 0; lt < 4; ++lt)
            #pragma unroll
            for (int e = 0; e < 4; ++e)
                zf[lt][e] = fminf(fmaxf(cin[lt][e], -5.f), 5.f);

        uc0 = un0; uc1 = un1;
    }

    // ---- epilogue: out = Wout @ z + bout ----
    short8 fz0 = mk8(pk2(zf[0][0], zf[0][1]), pk2(zf[0][2], zf[0][3]),
                     pk2(zf[1][0], zf[1][1]), pk2(zf[1][2], zf[1][3]));
    short8 fz1 = mk8(pk2(zf[2][0], zf[2][1]), pk2(zf[2][2], zf[2][3]),
                     pk2(zf[3][0], zf[3][1]), pk2(zf[3][2], zf[3][3]));
    #pragma unroll
    for (int mt = 0; mt < 2; ++mt) {
        const float* p0 = Wout + (mt * 16 + c) * NL + q * 8;
        short8 fa = pack8(*(const float4*)p0, *(const float4*)(p0 + 4));
        short8 fb = pack8(*(const float4*)(p0 + 32), *(const float4*)(p0 + 36));
        f32x4 cb = *(const f32x4*)(bout + mt * 16 + q * 4);
        f32x4 acc = __builtin_amdgcn_mfma_f32_16x16x32_bf16(fa, fz0, cb, 0, 0, 0);
        acc = __builtin_amdgcn_mfma_f32_16x16x32_bf16(fb, fz1, acc, 0, 0, 0);
        *(f32x4*)&out[(bbase + c) * NOUT + mt * 16 + q * 4] = acc;
    }
}

extern "C" void kernel_launch(void* const* d_in, const int* in_sizes, int n_in,
                              void* d_out, int out_size, void* d_ws, size_t ws_size,
                              hipStream_t stream) {
    const float* input = (const float*)d_in[0];
    const float* A     = (const float*)d_in[1];
    const float* W1    = (const float*)d_in[2];
    const float* W2    = (const float*)d_in[3];
    const float* h1    = (const float*)d_in[4];
    const float* h2    = (const float*)d_in[5];
    const float* C     = (const float*)d_in[6];
    const float* Wout  = (const float*)d_in[7];
    const float* bout  = (const float*)d_in[8];
    float* out = (float*)d_out;

    unsigned short* u16 = (unsigned short*)d_ws;   // 1024*16*1024 bf16 = 33.5 MB

    ugemm_mfma<<<dim3(512), dim3(256), 0, stream>>>(input, C, h1, u16);
    plrnn_scan_reg<<<dim3(16), dim3(64), 0, stream>>>(
        A, W1, W2, h2, u16, Wout, bout, out);
}

// Round 7
// 810.031 us; speedup vs baseline: 1.3095x; 1.1234x over previous
//
#include <hip/hip_runtime.h>
#include <hip/hip_bf16.h>

#define TSTEPS 1024
#define NIN 128
#define NL 64
#define NH 128
#define NOUT 32

typedef __attribute__((ext_vector_type(8))) short short8;
typedef __attribute__((ext_vector_type(4))) float f32x4;

// HW packed f32->bf16 RNE conversion: 1 inst instead of ~12-inst SW sequence.
// dst.lo = bf16(x), dst.hi = bf16(y) — same layout as __float22bfloat162_rn.
__device__ inline int pk2(float x, float y) {
    int r;
    asm("v_cvt_pk_bf16_f32 %0, %1, %2" : "=v"(r) : "v"(x), "v"(y));
    return r;
}
// clamp(x,-5,5) in one instruction (exact for non-NaN x; x is always bounded)
__device__ inline float clip5(float x) {
    float r;
    asm("v_med3_f32 %0, %1, %2, %3" : "=v"(r) : "v"(x), "v"(-5.0f), "v"(5.0f));
    return r;
}
__device__ inline short8 pack8(float4 r0, float4 r1) {
    union { short8 s; int i[4]; } f;
    f.i[0] = pk2(r0.x, r0.y); f.i[1] = pk2(r0.z, r0.w);
    f.i[2] = pk2(r1.x, r1.y); f.i[3] = pk2(r1.z, r1.w);
    return f.s;
}
__device__ inline short8 mk8(int a, int b, int cc, int d) {
    union { short8 s; int i[4]; } f;
    f.i[0] = a; f.i[1] = b; f.i[2] = cc; f.i[3] = d;
    return f.s;
}
__device__ inline void gload16(const unsigned short* g, unsigned short* l) {
    __builtin_amdgcn_global_load_lds(
        (const __attribute__((address_space(1))) unsigned int*)g,
        (__attribute__((address_space(3))) unsigned int*)l, 16, 0, 0);
}

// Latent permutation (verified passing, rounds 5-6):
//   l(lt, mloc) = 32*(lt>>1) + 8*(mloc>>2) + 4*(lt&1) + (mloc&3)
//   lH(i, mloc) = 64*(i>>2) + 32*((i>>1)&1) + 8*(mloc>>2) + 4*(i&1) + (mloc&3)
// u16 storage: per (t, group g) a 2 KB lane-linear block (round-6 layout).

// ---------------------------------------------------------------------------
// Pass 1: u' = bf16(C~ @ s + h1~), stored in lane-linear block order.
// ---------------------------------------------------------------------------
__launch_bounds__(256, 1)
__global__ void ugemm_mfma(const float* __restrict__ input,
                           const float* __restrict__ C,
                           const float* __restrict__ h1,
                           unsigned short* __restrict__ u16) {
    const int lane = threadIdx.x & 63;
    const int wv   = threadIdx.x >> 6;
    const int c = lane & 15;
    const int q = lane >> 4;
    const long wbase = ((long)blockIdx.x * 4 + wv) * 128;  // first row (b*1024+t)

    short8 cA[4][4];
    #pragma unroll
    for (int mt = 0; mt < 4; ++mt) {
        const int row = 32 * (mt >> 1) + 8 * (c >> 2) + 4 * (mt & 1) + (c & 3);
        #pragma unroll
        for (int kf = 0; kf < 4; ++kf) {
            const float* p = C + row * NIN + kf * 32 + q * 8;
            cA[mt][kf] = pack8(*(const float4*)p, *(const float4*)(p + 4));
        }
    }
    f32x4 h1f[4];
    #pragma unroll
    for (int mt = 0; mt < 4; ++mt)
        h1f[mt] = *(const f32x4*)(h1 + 32 * (mt >> 1) + 4 * (mt & 1) + 8 * q);

    float4 raw[8], rawn[8];
    {
        const float* sr = input + (wbase + c) * NIN;
        #pragma unroll
        for (int kf = 0; kf < 4; ++kf) {
            raw[2*kf]   = *(const float4*)(sr + kf * 32 + q * 8);
            raw[2*kf+1] = *(const float4*)(sr + kf * 32 + q * 8 + 4);
        }
    }

    for (int it = 0; it < 8; ++it) {
        if (it < 7) {
            const float* sr = input + (wbase + (it + 1) * 16 + c) * NIN;
            #pragma unroll
            for (int kf = 0; kf < 4; ++kf) {
                rawn[2*kf]   = *(const float4*)(sr + kf * 32 + q * 8);
                rawn[2*kf+1] = *(const float4*)(sr + kf * 32 + q * 8 + 4);
            }
        }
        short8 bf[4];
        #pragma unroll
        for (int kf = 0; kf < 4; ++kf)
            bf[kf] = pack8(raw[2*kf], raw[2*kf+1]);
        long rr = wbase + it * 16 + c;
        int b = (int)(rr >> 10), t = (int)(rr & 1023);
        const int g = b >> 4, cb = b & 15;
        unsigned short* ubase = u16 + ((size_t)t * 16 + g) * 1024 + q * 128 + cb * 8;
        #pragma unroll
        for (int mt = 0; mt < 4; ++mt) {
            f32x4 acc = __builtin_amdgcn_mfma_f32_16x16x32_bf16(cA[mt][0], bf[0], h1f[mt], 0, 0, 0);
            acc = __builtin_amdgcn_mfma_f32_16x16x32_bf16(cA[mt][1], bf[1], acc, 0, 0, 0);
            acc = __builtin_amdgcn_mfma_f32_16x16x32_bf16(cA[mt][2], bf[2], acc, 0, 0, 0);
            acc = __builtin_amdgcn_mfma_f32_16x16x32_bf16(cA[mt][3], bf[3], acc, 0, 0, 0);
            *(int2*)(ubase + (mt >> 1) * 512 + (mt & 1) * 4) =
                make_int2(pk2(acc[0], acc[1]), pk2(acc[2], acc[3]));
        }
        #pragma unroll
        for (int j = 0; j < 8; ++j) raw[j] = rawn[j];
    }
}

// ---------------------------------------------------------------------------
// Pass 2: register-only scan, HW bf16 conversion, global_load_lds u' ring.
// Grid 16 WGs x 64 thr; one wave owns one 16-batch group. No barriers.
// ---------------------------------------------------------------------------
__launch_bounds__(64, 1)
__global__ void plrnn_scan_reg(const float* __restrict__ A,
                               const float* __restrict__ W1,
                               const float* __restrict__ W2,
                               const float* __restrict__ h2,
                               const unsigned short* __restrict__ u16,
                               const float* __restrict__ Wout,
                               const float* __restrict__ bout,
                               float* __restrict__ out) {
    __shared__ __attribute__((aligned(16))) unsigned short ulds[8 * 1024];  // 16 KB ring

    const int lane = threadIdx.x & 63;
    const int c = lane & 15;               // batch col
    const int q = lane >> 4;               // quad
    const int g = blockIdx.x;
    const int bbase = g * 16;

    // ---- W2-tilde ----
    short8 aw2[8][2];
    #pragma unroll
    for (int i = 0; i < 8; ++i) {
        const int row = 64 * (i >> 2) + 32 * ((i >> 1) & 1) + 8 * (c >> 2)
                      + 4 * (i & 1) + (c & 3);
        #pragma unroll
        for (int kt = 0; kt < 2; ++kt) {
            const float* p = W2 + row * NL + kt * 32 + q * 8;
            aw2[i][kt] = pack8(*(const float4*)p, *(const float4*)(p + 4));
        }
    }
    // ---- W1-tilde ----
    short8 aw1[4][4];
    #pragma unroll
    for (int lt = 0; lt < 4; ++lt) {
        const int row = 32 * (lt >> 1) + 8 * (c >> 2) + 4 * (lt & 1) + (c & 3);
        #pragma unroll
        for (int kt = 0; kt < 4; ++kt) {
            const float* p = W1 + row * NH + kt * 32 + q * 8;
            aw1[lt][kt] = pack8(*(const float4*)p, *(const float4*)(p + 4));
        }
    }
    f32x4 h2f[8];
    #pragma unroll
    for (int i = 0; i < 8; ++i)
        h2f[i] = *(const f32x4*)(h2 + 64 * (i >> 2) + 32 * ((i >> 1) & 1)
                                 + 4 * (i & 1) + 8 * q);
    f32x4 af[4];
    #pragma unroll
    for (int lt = 0; lt < 4; ++lt)
        af[lt] = *(const f32x4*)(A + 32 * (lt >> 1) + 4 * (lt & 1) + 8 * q);

    f32x4 zf[4] = {{0.f,0.f,0.f,0.f},{0.f,0.f,0.f,0.f},
                   {0.f,0.f,0.f,0.f},{0.f,0.f,0.f,0.f}};

    // per-lane global source base (16B per lane, second KB at +512 shorts)
    const unsigned short* gs0 = u16 + (size_t)g * 1024 + lane * 8;

    // ---- prologue: stage steps 0..3 into ring slots 0..3 ----
    #pragma unroll
    for (int s0 = 0; s0 < 4; ++s0) {
        const unsigned short* p0 = gs0 + (size_t)s0 * 16384;
        unsigned short* l0 = &ulds[s0 * 1024];
        gload16(p0, l0);
        gload16(p0 + 512, l0 + 512);
    }
    __builtin_amdgcn_sched_barrier(0);
    asm volatile("s_waitcnt vmcnt(6)" ::: "memory");   // step 0 landed
    __builtin_amdgcn_sched_barrier(0);
    int4 uc0 = *(const int4*)(&ulds[0]   + lane * 8);
    int4 uc1 = *(const int4*)(&ulds[512] + lane * 8);

    for (int s = 0; s < TSTEPS; ++s) {
        // 1. issue staging for step s+4 (fire-and-forget)
        {
            const int tt = (s + 4 < TSTEPS) ? s + 4 : TSTEPS - 1;
            const unsigned short* p0 = gs0 + (size_t)tt * 16384;
            unsigned short* l0 = &ulds[((s + 4) & 7) * 1024];
            gload16(p0, l0);
            gload16(p0 + 512, l0 + 512);
        }
        __builtin_amdgcn_sched_barrier(0);
        asm volatile("s_waitcnt vmcnt(4)" ::: "memory");   // step s+1 landed
        __builtin_amdgcn_sched_barrier(0);
        // 2. LDS -> reg prefetch of step s+1 (consumed next iteration)
        const unsigned short* slot = &ulds[((s + 1) & 7) * 1024];
        int4 un0 = *(const int4*)(slot + lane * 8);
        int4 un1 = *(const int4*)(slot + 512 + lane * 8);

        // 3. compute step s (same values/orderings as rounds 5-6)
        short8 bz0 = mk8(pk2(zf[0][0], zf[0][1]), pk2(zf[0][2], zf[0][3]),
                         pk2(zf[1][0], zf[1][1]), pk2(zf[1][2], zf[1][3]));
        short8 bz1 = mk8(pk2(zf[2][0], zf[2][1]), pk2(zf[2][2], zf[2][3]),
                         pk2(zf[3][0], zf[3][1]), pk2(zf[3][2], zf[3][3]));

        f32x4 cin[4];
        {
            const int ia0 = uc0.x, ib0 = uc0.y, ia1 = uc0.z, ib1 = uc0.w;
            const int ia2 = uc1.x, ib2 = uc1.y, ia3 = uc1.z, ib3 = uc1.w;
            cin[0][0] = fmaf(zf[0][0], af[0][0], __int_as_float(ia0 << 16));
            cin[0][1] = fmaf(zf[0][1], af[0][1], __int_as_float(ia0 & 0xffff0000));
            cin[0][2] = fmaf(zf[0][2], af[0][2], __int_as_float(ib0 << 16));
            cin[0][3] = fmaf(zf[0][3], af[0][3], __int_as_float(ib0 & 0xffff0000));
            cin[1][0] = fmaf(zf[1][0], af[1][0], __int_as_float(ia1 << 16));
            cin[1][1] = fmaf(zf[1][1], af[1][1], __int_as_float(ia1 & 0xffff0000));
            cin[1][2] = fmaf(zf[1][2], af[1][2], __int_as_float(ib1 << 16));
            cin[1][3] = fmaf(zf[1][3], af[1][3], __int_as_float(ib1 & 0xffff0000));
            cin[2][0] = fmaf(zf[2][0], af[2][0], __int_as_float(ia2 << 16));
            cin[2][1] = fmaf(zf[2][1], af[2][1], __int_as_float(ia2 & 0xffff0000));
            cin[2][2] = fmaf(zf[2][2], af[2][2], __int_as_float(ib2 << 16));
            cin[2][3] = fmaf(zf[2][3], af[2][3], __int_as_float(ib2 & 0xffff0000));
            cin[3][0] = fmaf(zf[3][0], af[3][0], __int_as_float(ia3 << 16));
            cin[3][1] = fmaf(zf[3][1], af[3][1], __int_as_float(ia3 & 0xffff0000));
            cin[3][2] = fmaf(zf[3][2], af[3][2], __int_as_float(ib3 << 16));
            cin[3][3] = fmaf(zf[3][3], af[3][3], __int_as_float(ib3 & 0xffff0000));
        }

        // MFMA1: 8 H-tiles = relu(W2~ @ z + h2~), in registers
        f32x4 ha[8];
        #pragma unroll
        for (int i = 0; i < 8; ++i) {
            ha[i] = __builtin_amdgcn_mfma_f32_16x16x32_bf16(aw2[i][0], bz0, h2f[i], 0, 0, 0);
            ha[i] = __builtin_amdgcn_mfma_f32_16x16x32_bf16(aw2[i][1], bz1, ha[i], 0, 0, 0);
        }
        short8 bh[4];
        #pragma unroll
        for (int kt = 0; kt < 4; ++kt) {
            const int i0 = 2 * kt, i1 = 2 * kt + 1;
            bh[kt] = mk8(
                pk2(fmaxf(ha[i0][0], 0.f), fmaxf(ha[i0][1], 0.f)),
                pk2(fmaxf(ha[i0][2], 0.f), fmaxf(ha[i0][3], 0.f)),
                pk2(fmaxf(ha[i1][0], 0.f), fmaxf(ha[i1][1], 0.f)),
                pk2(fmaxf(ha[i1][2], 0.f), fmaxf(ha[i1][3], 0.f)));
        }
        // MFMA2: z' = clip(cin + W1~ @ H)
        #pragma unroll
        for (int kt = 0; kt < 4; ++kt)
            #pragma unroll
            for (int lt = 0; lt < 4; ++lt)
                cin[lt] = __builtin_amdgcn_mfma_f32_16x16x32_bf16(aw1[lt][kt], bh[kt], cin[lt], 0, 0, 0);
        #pragma unroll
        for (int lt = 0; lt < 4; ++lt)
            #pragma unroll
            for (int e = 0; e < 4; ++e)
                zf[lt][e] = clip5(cin[lt][e]);

        uc0 = un0; uc1 = un1;
    }

    // ---- epilogue: out = Wout @ z + bout ----
    short8 fz0 = mk8(pk2(zf[0][0], zf[0][1]), pk2(zf[0][2], zf[0][3]),
                     pk2(zf[1][0], zf[1][1]), pk2(zf[1][2], zf[1][3]));
    short8 fz1 = mk8(pk2(zf[2][0], zf[2][1]), pk2(zf[2][2], zf[2][3]),
                     pk2(zf[3][0], zf[3][1]), pk2(zf[3][2], zf[3][3]));
    #pragma unroll
    for (int mt = 0; mt < 2; ++mt) {
        const float* p0 = Wout + (mt * 16 + c) * NL + q * 8;
        short8 fa = pack8(*(const float4*)p0, *(const float4*)(p0 + 4));
        short8 fb = pack8(*(const float4*)(p0 + 32), *(const float4*)(p0 + 36));
        f32x4 cb = *(const f32x4*)(bout + mt * 16 + q * 4);
        f32x4 acc = __builtin_amdgcn_mfma_f32_16x16x32_bf16(fa, fz0, cb, 0, 0, 0);
        acc = __builtin_amdgcn_mfma_f32_16x16x32_bf16(fb, fz1, acc, 0, 0, 0);
        *(f32x4*)&out[(bbase + c) * NOUT + mt * 16 + q * 4] = acc;
    }
}

extern "C" void kernel_launch(void* const* d_in, const int* in_sizes, int n_in,
                              void* d_out, int out_size, void* d_ws, size_t ws_size,
                              hipStream_t stream) {
    const float* input = (const float*)d_in[0];
    const float* A     = (const float*)d_in[1];
    const float* W1    = (const float*)d_in[2];
    const float* W2    = (const float*)d_in[3];
    const float* h1    = (const float*)d_in[4];
    const float* h2    = (const float*)d_in[5];
    const float* C     = (const float*)d_in[6];
    const float* Wout  = (const float*)d_in[7];
    const float* bout  = (const float*)d_in[8];
    float* out = (float*)d_out;

    unsigned short* u16 = (unsigned short*)d_ws;   // 1024*16*1024 bf16 = 33.5 MB

    ugemm_mfma<<<dim3(512), dim3(256), 0, stream>>>(input, C, h1, u16);
    plrnn_scan_reg<<<dim3(16), dim3(64), 0, stream>>>(
        A, W1, W2, h2, u16, Wout, bout, out);
}